// Round 5
// baseline (76.050 us; speedup 1.0000x reference)
//
#include <hip/hip_runtime.h>
#include <math.h>

#define K_DCG 512
// SIGMA == 1.0f folded in. N = 8192 fixed by harness (code assumes N == 8192).

typedef float v2f __attribute__((ext_vector_type(2)));

// ---------------------------------------------------------------------------
// R23: barrier-free wave-autonomous fused exact kernel (single dispatch).
// Post-mortems: R20/R21 fused ~30us despite ~10us issue model; R21 proved
// pipes aren't the limit (8x fewer LDS instrs = no change). Remaining theory:
// the 16-barrier chunk structure serializes build (log2f/exp latency chains)
// against sweep across all 16 waves. This version removes ALL main-loop
// barriers: wave w owns j-slice [w*512,(w+1)*512), processed as 8 mini-chunks
// of 64 j: each lane builds ONE record into the wave's PRIVATE LDS region
// (wave-synchronous: DS ops from a single wave execute in order; compiler
// inserts lgkmcnt), then sweeps 4 j x 8 register-resident i's per lane.
// Read pattern j = k*16 + jslot => 16 consecutive float4 per phase = 2-way
// bank aliasing (free, m136). Build trans-latency overlaps sweep issue.
// Math (verified R13..R21):
//   lam_i = Ninv*[ P_i + a_i*S1_i + Sa_i - g_i*Sd_i - d_i*Sg_i ]
//   P_i   = g_i*sufD_b - a_i*sufC_b - sufGD_b + d_i*sufG_b   (buckets > b_i)
//   S*_i  = sum_j w_j / (1 + e^{p_i} * e^{-p_j}),  w = {1, d_j, g_j, g_j*d_j}
// Coverage: wave w sweeps its 512 j's for the block's 32 i's; per mini-chunk
// lane (ig=lane&3, jslot=lane>>2) sweeps j = k*16+jslot (k=0..3) x i-octet ig
// -> all (i,j) covered once across 16 waves. Butterfly closure over the 16
// same-ig lanes (xor 4,8,16,32), then 16-wave LDS combine (verified R21).
// Single dispatch, no workspace, no atomics, no cross-block dependency.
// ---------------------------------------------------------------------------

__global__ __launch_bounds__(1024) void lambdarank_kernel(
        const float* __restrict__ pred, const float* __restrict__ targ,
        float* __restrict__ out, int N) {
    const int tid = threadIdx.x, bid = blockIdx.x;
    const int wave = tid >> 6, lane = tid & 63;
    const int ig    = lane & 3;                // i-octet group (8 i's)
    const int jslot = lane >> 2;               // 0..15: j-slot within mini-chunk

    __shared__ int s_cnt[4][256];              // ge-level 32-chunk counts -> excl prefix
    __shared__ int s_tot4[4];
    __shared__ int s_base[6];
    __shared__ float s_red[16][5];
    __shared__ float s_scal[21];  // [0]=ninv [1..5]=sufD [6..10]=sufG [11..15]=sufGD [16..20]=sufC
    __shared__ float4 s_wr[16][64];            // wave-private mini-chunk records
    __shared__ v2f s_pdg[16][4][8];            // per-wave {Sd,Sg} partials
    __shared__ v2f s_poa[16][4][8];            // per-wave {S1,Sa} partials

    // my 8 i's: e^{+p_i} in registers (broadcast loads, one-time)
    float exi[8];
    #pragma unroll
    for (int io = 0; io < 8; io++)
        exi[io] = __expf(pred[bid * 32 + ig * 8 + io]);

    // 1. ge-level counts over 32-element chunks (256 scan threads, verified)
    if (tid < 256) {
        int c1 = 0, c2 = 0, c3 = 0, c4 = 0;
        const float4* t4 = (const float4*)targ;
        #pragma unroll
        for (int k = 0; k < 8; k++) {
            const float4 v = t4[tid * 8 + k];
            #pragma unroll
            for (int e = 0; e < 4; e++) {
                const float tv = ((const float*)&v)[e];
                c1 += (tv >= 1.0f); c2 += (tv >= 2.0f);
                c3 += (tv >= 3.0f); c4 += (tv >= 4.0f);
            }
        }
        s_cnt[0][tid] = c1; s_cnt[1][tid] = c2;
        s_cnt[2][tid] = c3; s_cnt[3][tid] = c4;
    }
    __syncthreads();

    // 2. exclusive scan over the 256 chunk-counts (wave w -> ge-level w+1)
    if (tid < 256) {
        int carry = 0;
        for (int c = 0; c < 4; c++) {
            const int orig = s_cnt[wave][c * 64 + lane];
            int v = orig;
            #pragma unroll
            for (int off = 1; off < 64; off <<= 1) {
                const int nv = __shfl_up(v, off, 64);
                if (lane >= off) v += nv;
            }
            s_cnt[wave][c * 64 + lane] = v - orig + carry;
            carry += __shfl(v, 63, 64);
        }
        if (lane == 0) s_tot4[wave] = carry;
    }
    __syncthreads();

    // 3. bucket bases: base[b] = #elements with t < b
    if (tid < 6)
        s_base[tid] = (tid == 0) ? 0 : (tid == 5 ? N : N - s_tot4[tid - 1]);
    __syncthreads();

    // 4. D_ge sums + maxDCG at 1024-thread stride, 16-wave reduce (R22-K2
    //    machinery). tid==0 then computes suffix scalars while other waves
    //    proceed: s_scal/s_red only read in the epilogue, which is ordered
    //    by the final __syncthreads.
    {
        const int base1 = N - s_tot4[0], base2 = N - s_tot4[1];
        const int base3 = N - s_tot4[2], base4 = N - s_tot4[3];
        float Dge1 = 0, Dge2 = 0, Dge3 = 0, Dge4 = 0, md = 0;
        for (int r = tid; r < N; r += 1024) {
            const float term = __builtin_amdgcn_rcpf(log2f((float)(r + 2)));
            Dge1 += (r >= base1) ? term : 0.0f;
            Dge2 += (r >= base2) ? term : 0.0f;
            Dge3 += (r >= base3) ? term : 0.0f;
            Dge4 += (r >= base4) ? term : 0.0f;
        }
        for (int pos = tid + 1; pos <= K_DCG; pos += 1024) {
            const int r0 = N - pos;
            const int b = (r0 >= base1) + (r0 >= base2) + (r0 >= base3) + (r0 >= base4);
            md += ((float)(1 << b) - 1.0f) * __builtin_amdgcn_rcpf(log2f((float)(pos + 1)));
        }
        #pragma unroll
        for (int off = 32; off; off >>= 1) {
            Dge1 += __shfl_down(Dge1, off, 64);
            Dge2 += __shfl_down(Dge2, off, 64);
            Dge3 += __shfl_down(Dge3, off, 64);
            Dge4 += __shfl_down(Dge4, off, 64);
            md   += __shfl_down(md,   off, 64);
        }
        if (lane == 0) {
            s_red[wave][0] = Dge1; s_red[wave][1] = Dge2;
            s_red[wave][2] = Dge3; s_red[wave][3] = Dge4; s_red[wave][4] = md;
        }
    }
    __syncthreads();
    if (tid == 0) {
        float Dge[6];
        Dge[0] = 0.0f; Dge[5] = 0.0f;
        float mdt = 0.0f;
        #pragma unroll
        for (int k = 1; k <= 4; k++) Dge[k] = 0.0f;
        #pragma unroll
        for (int w = 0; w < 16; w++) {
            Dge[1] += s_red[w][0]; Dge[2] += s_red[w][1];
            Dge[3] += s_red[w][2]; Dge[4] += s_red[w][3];
            mdt    += s_red[w][4];
        }
        s_scal[0] = __builtin_amdgcn_rcpf(mdt);            // Ninv
        float sufG = 0.0f, sufGD = 0.0f;
        for (int b = 4; b >= 0; b--) {
            s_scal[1 + b]  = Dge[b + 1];                   // sufD_b
            s_scal[6 + b]  = sufG;
            s_scal[11 + b] = sufGD;
            s_scal[16 + b] = (float)(N - s_base[b + 1]);   // sufC_b
            const float Db = Dge[b] - Dge[b + 1];
            const float gb = (float)(1 << b);
            sufG  += gb * (float)(s_base[b + 1] - s_base[b]);
            sufGD += gb * Db;
        }
    }

    // 5. main loop: wave-autonomous, ZERO barriers. Wave w: slice
    //    [w*512, w*512+512) in 8 mini-chunks of 64 (64-aligned windows ->
    //    verbatim ballot-rank machinery; all 64 lanes active -> exact).
    float4* const wr = s_wr[wave];
    v2f dg[8], oa[8];                          // per-i {Sd,Sg}, {S1,Sa}
    #pragma unroll
    for (int io = 0; io < 8; io++) { dg[io] = 0.0f; oa[io] = 0.0f; }

    for (int c = 0; c < 8; c++) {
        // build: one record per lane into the wave's private region
        {
            const int idx = wave * 512 + c * 64 + lane;
            const float tv = targ[idx], pv = pred[idx];
            const int b = (tv >= 1.0f) + (tv >= 2.0f) + (tv >= 3.0f) + (tv >= 4.0f);
            unsigned long long mym = 0;
            #pragma unroll
            for (int bb = 0; bb < 5; bb++) {
                const unsigned long long m = __ballot(b == bb);
                if (b == bb) mym = m;
            }
            const unsigned long long half_mask =
                (lane < 32) ? 0x00000000FFFFFFFFull : 0xFFFFFFFF00000000ull;
            const int tie = __popcll(mym & half_mask & ((1ull << lane) - 1ull));
            const int ch = idx >> 5;           // global 32-chunk (half-wave aligned)
            const int pA = (b == 0) ? ch * 32 : s_cnt[b - 1][ch];
            const int pB = (b == 4) ? 0 : s_cnt[b][ch];
            const int rank = s_base[b] + (pA - pB) + tie;
            const float d = __builtin_amdgcn_rcpf(__log2f((float)(rank + 2)));
            const float g = (float)(1 << b);
            wr[lane] = make_float4(d, g, __expf(-pv), g * d);
        }
        // wave-synchronous: DS ops from one wave execute in order; the
        // compiler's lgkmcnt covers the write->read dependency. No barrier.
        // sweep: 4 j's (j = k*16 + jslot: consecutive float4 per k-phase ->
        // 2-way bank aliasing = free) x 8 register-resident i's.
        #pragma unroll
        for (int k = 0; k < 4; k++) {
            const float4 e = wr[k * 16 + jslot];
            v2f wdg; wdg.x = e.x; wdg.y = e.y;
            v2f woa; woa.x = 1.0f; woa.y = e.w;
            #pragma unroll
            for (int io = 0; io < 8; io++) {
                const float r = __builtin_amdgcn_rcpf(fmaf(exi[io], e.z, 1.0f));
                dg[io] += r * wdg;             // v_pk_fma_f32
                oa[io] += r * woa;
            }
        }
    }

    // 6. reduce across the 16 same-ig lanes of each wave (butterfly closure
    //    {ig+4m} = xor span of 4,8,16,32), then stage per-wave partials.
    #pragma unroll
    for (int io = 0; io < 8; io++) {
        #pragma unroll
        for (int off = 4; off <= 32; off <<= 1) {
            dg[io].x += __shfl_xor(dg[io].x, off, 64);
            dg[io].y += __shfl_xor(dg[io].y, off, 64);
            oa[io].x += __shfl_xor(oa[io].x, off, 64);
            oa[io].y += __shfl_xor(oa[io].y, off, 64);
        }
    }
    if (lane < 4) {                            // lane == its ig
        #pragma unroll
        for (int io = 0; io < 8; io++) {
            s_pdg[wave][lane][io] = dg[io];
            s_poa[wave][lane][io] = oa[io];
        }
    }
    __syncthreads();

    // 7. epilogue: 32 threads (wave 0, lanes 0..31), one i each; block's i's
    //    = one 32-chunk so the ballot tie-break over lanes 0..31 is exact
    //    (lanes 32..63 inactive -> ballot bits 0). i_local = ig*8+io ->
    //    partials at [w][tid>>3][tid&7] (verified R21).
    if (tid < 32) {
        v2f sdg = 0.0f, soa = 0.0f;
        #pragma unroll
        for (int w = 0; w < 16; w++) {
            sdg += s_pdg[w][tid >> 3][tid & 7];
            soa += s_poa[w][tid >> 3][tid & 7];
        }
        const float Sd = sdg.x, Sg = sdg.y, S1 = soa.x, Sa = soa.y;

        const int i = bid * 32 + tid;
        const float tv = targ[i];
        const int b = (tv >= 1.0f) + (tv >= 2.0f) + (tv >= 3.0f) + (tv >= 4.0f);
        unsigned long long mym = 0;
        #pragma unroll
        for (int bb = 0; bb < 5; bb++) {
            const unsigned long long m = __ballot(b == bb);
            if (b == bb) mym = m;
        }
        const int tie = __popcll(mym & ((1ull << tid) - 1ull));
        const int ch = i >> 5;                 // == bid
        const int pA = (b == 0) ? ch * 32 : s_cnt[b - 1][ch];
        const int pB = (b == 4) ? 0 : s_cnt[b][ch];
        const int rank = s_base[b] + (pA - pB) + tie;
        const float d = __builtin_amdgcn_rcpf(__log2f((float)(rank + 2)));
        const float g = (float)(1 << b);
        const float a = g * d;
        const float P = g * s_scal[1 + b] - a * s_scal[16 + b]
                        - s_scal[11 + b] + d * s_scal[6 + b];
        out[i] = s_scal[0] * (P + a * S1 + Sa - g * Sd - d * Sg);
    }
}

// ---------------------------------------------------------------------------
extern "C" void kernel_launch(void* const* d_in, const int* in_sizes, int n_in,
                              void* d_out, int out_size, void* d_ws, size_t ws_size,
                              hipStream_t stream) {
    const float* pred = (const float*)d_in[0];
    const float* targ = (const float*)d_in[1];
    float* out = (float*)d_out;
    const int N = in_sizes[0];   // 8192
    (void)d_ws; (void)ws_size;   // workspace unused: no table, no atomics

    lambdarank_kernel<<<256, 1024, 0, stream>>>(pred, targ, out, N);
}